// Round 5
// baseline (208.431 us; speedup 1.0000x reference)
//
#include <hip/hip_runtime.h>

#define GRID_N 112
#define O_MAX 48
#define HW_N (GRID_N * GRID_N)   // 12544
#define NT 448                   // 7 independent waves; wave w owns row strip th=w

typedef _Float16 half8 __attribute__((ext_vector_type(8)));
typedef float    f32x4 __attribute__((ext_vector_type(4)));

// channel[b,h,w] = 0.5 + sum_k A[h,k]*B[w,k], masked by road_mask.
// A rows carry sign/scale: k<n -> -0.5*obj gauss, k==n -> +0.5*goal gauss, k>n -> 0.
//
// FULLY WAVE-PRIVATE version: no LDS, no barriers, no inter-wave coupling.
// Each wave builds its A-fragment (16 rows) AND its B-fragments (16 cols/tile)
// directly in registers via exp -- redundant exp work (~112 extra exps/wave,
// ~0.3 us chip-wide VALU) in exchange for removing the build->barrier->consume
// phase chain that serialized every prior version. Each wave is a pure
// load -> exp -> MFMA -> store stream; 14336 independent waves.
__global__ __launch_bounds__(NT) void goalmap_kernel(
    const float* __restrict__ xL, const float* __restrict__ yL,
    const float* __restrict__ obj_list, const int* __restrict__ obj_num,
    const int* __restrict__ road_mask, float* __restrict__ out)
{
    constexpr float INV = 1.0f / (2.0f * 5.0f * 5.0f);  // SIGMA = 5.0

    const int b   = blockIdx.x;
    const int tid = threadIdx.x;
    const int lane = tid & 63;
    const int wid  = tid >> 6;                  // 0..6: row strip
    const int m    = lane & 15;
    const int quad = lane >> 4;

    const int n  = obj_num[b];                  // uniform -> scalar
    const float xl = xL[b];
    const float yl = yL[b];
    const float* ob = obj_list + (size_t)b * (O_MAX * 2);
    const int*   rm = road_mask + (size_t)b * HW_N;
    float*       op = out       + (size_t)b * HW_N;

    // ---- (1) obj-coordinate gathers FIRST in the vmcnt FIFO (consumed first:
    //      waiting on them must not require draining the mask loads).
    float ax0[8], ay0[8], ax1[8], ay1[8];
    #pragma unroll
    for (int j = 0; j < 8; ++j) {
        int k = quad * 8 + j;                   // k in [0,32)
        ax0[j] = ob[k * 2 + 1];                 // x of obj k (always in-bounds)
        ay0[j] = ob[k * 2];                     // y of obj k
        bool g = (k + 32 < n);                  // guard: k+32 may exceed O_MAX
        ax1[j] = g ? ob[(k + 32) * 2 + 1] : 0.f;
        ay1[j] = g ? ob[(k + 32) * 2]     : 0.f;
    }
    __builtin_amdgcn_sched_barrier(0);          // pin issue order: coords < masks

    // ---- (2) mask loads SECOND (consumed last, at the stores)
    int mpf[7][4];
    const int h0 = wid * 16 + quad * 4;         // C/D row base for this lane
    #pragma unroll
    for (int i = 0; i < 7; ++i) {
        int base = h0 * GRID_N + i * 16 + m;
        #pragma unroll
        for (int r = 0; r < 4; ++r)
            mpf[i][r] = rm[base + r * GRID_N];
    }
    __builtin_amdgcn_sched_barrier(0);

    const int ksteps = (n >= 32) ? 2 : 1;       // wave-uniform

    // ---- (3) A-fragments in registers (signed/scaled): rows wid*16+m
    const float fh = (float)(wid * 16 + m);
    half8 a0, a1;
    #pragma unroll
    for (int j = 0; j < 8; ++j) {
        int k = quad * 8 + j;
        float val = 0.f;
        if (k <= n) {
            float cx = (k < n) ? ax0[j] : xl;
            float s  = (k < n) ? -0.5f  : 0.5f;
            float d  = fh - cx;
            val = s * __expf(-d * d * INV);
        }
        a0[j] = (_Float16)val;
    }
    if (ksteps == 2) {
        #pragma unroll
        for (int j = 0; j < 8; ++j) {
            int k = quad * 8 + j + 32;
            float val = 0.f;
            if (k <= n) {
                float cx = (k < n) ? ax1[j] : xl;
                float s  = (k < n) ? -0.5f  : 0.5f;
                float d  = fh - cx;
                val = s * __expf(-d * d * INV);
            }
            a1[j] = (_Float16)val;
        }
    }

    // ---- (4) tile sweep: B-fragments built privately per tile (16 exps),
    //      MFMA, mask select, store. No sync with any other wave, ever.
    #pragma unroll
    for (int tw = 0; tw < 7; ++tw) {
        const float fw = (float)(tw * 16 + m);  // this lane's column
        half8 b0;
        #pragma unroll
        for (int j = 0; j < 8; ++j) {
            int k = quad * 8 + j;
            float val = 0.f;
            if (k <= n) {
                float cy = (k < n) ? ay0[j] : yl;
                float d  = fw - cy;
                val = __expf(-d * d * INV);
            }
            b0[j] = (_Float16)val;
        }
        f32x4 acc = {0.f, 0.f, 0.f, 0.f};
        acc = __builtin_amdgcn_mfma_f32_16x16x32_f16(a0, b0, acc, 0, 0, 0);
        if (ksteps == 2) {
            half8 b1;
            #pragma unroll
            for (int j = 0; j < 8; ++j) {
                int k = quad * 8 + j + 32;
                float val = 0.f;
                if (k <= n) {
                    float cy = (k < n) ? ay1[j] : yl;
                    float d  = fw - cy;
                    val = __expf(-d * d * INV);
                }
                b1[j] = (_Float16)val;
            }
            acc = __builtin_amdgcn_mfma_f32_16x16x32_f16(a1, b1, acc, 0, 0, 0);
        }

        const int w0 = tw * 16 + m;
        #pragma unroll
        for (int r = 0; r < 4; ++r) {
            float v = 0.5f + acc[r];
            v = (mpf[tw][r] == 0) ? 0.f : v;
            op[(h0 + r) * GRID_N + w0] = v;
        }
    }
}

extern "C" void kernel_launch(void* const* d_in, const int* in_sizes, int n_in,
                              void* d_out, int out_size, void* d_ws, size_t ws_size,
                              hipStream_t stream) {
    const float* xL        = (const float*)d_in[0];
    const float* yL        = (const float*)d_in[1];
    const float* obj_list  = (const float*)d_in[2];
    const int*   obj_num   = (const int*)d_in[3];
    const int*   road_mask = (const int*)d_in[4];
    float*       out       = (float*)d_out;
    const int B = in_sizes[0];  // 2048

    goalmap_kernel<<<B, NT, 0, stream>>>(xL, yL, obj_list, obj_num, road_mask, out);
}

// Round 6
// 197.053 us; speedup vs baseline: 1.0577x; 1.0577x over previous
//
#include <hip/hip_runtime.h>

#define GRID_N 112
#define O_MAX 48
#define HW_N (GRID_N * GRID_N)   // 12544
#define NT 448                   // 7 waves; wave w owns rows w*16..w*16+15
#define SDW (16 * GRID_N)        // 1792 dwords per strip (contiguous in memory)

typedef _Float16 half8 __attribute__((ext_vector_type(8)));
typedef float    f32x4 __attribute__((ext_vector_type(4)));
typedef float    f32x2 __attribute__((ext_vector_type(2)));
typedef int      i32x4 __attribute__((ext_vector_type(4)));

// channel[b,h,w] = 0.5 + sum_k ex[h,k]*ey[w,k], masked by road_mask.
// SWAPPED MFMA (first operand = ey): lane holds out[h=m][w=tw*16+quad*4+r],
// i.e. 4 consecutive columns -> f32x4. Wave-private LDS transpose linearizes
// the strip so ALL global traffic (mask loads, output stores) is
// dwordx4/lane over contiguous 1024 B/instruction = full 128 B lines.
// Prior versions' 64 B segments halved bytes-per-outstanding-request ->
// bandwidth cap at ~2.3 TB/s regardless of occupancy. No barriers anywhere.
__global__ __launch_bounds__(NT) void goalmap_kernel(
    const float* __restrict__ xL, const float* __restrict__ yL,
    const float* __restrict__ obj_list, const int* __restrict__ obj_num,
    const int* __restrict__ road_mask, float* __restrict__ out)
{
    constexpr float INV = 1.0f / (2.0f * 5.0f * 5.0f);  // SIGMA = 5.0

    __shared__ float lds[7][SDW];               // 7 x 7168 B, wave-private

    const int b    = blockIdx.x;
    const int tid  = threadIdx.x;
    const int lane = tid & 63;
    const int wid  = tid >> 6;                  // 0..6: strip
    const int m    = lane & 15;
    const int quad = lane >> 4;

    const int n  = obj_num[b];                  // uniform
    const float xl = xL[b];
    const float yl = yL[b];
    const float* ob = obj_list + (size_t)b * (O_MAX * 2);
    const int*   rm = road_mask + (size_t)b * HW_N + wid * SDW;
    float*       op = out       + (size_t)b * HW_N + wid * SDW;

    // ---- (1) obj-coordinate gathers FIRST in the vmcnt FIFO (consumed first)
    f32x2 oc0[8], oc1[8];                       // (y, x) of obj k / k+32
    #pragma unroll
    for (int j = 0; j < 8; ++j) {
        int k = quad * 8 + j;                   // k in [0,32)
        oc0[j] = *(const f32x2*)&ob[k * 2];     // always in-bounds
        bool g = (k + 32 < n);
        f32x2 z = {0.f, 0.f};
        oc1[j] = g ? *(const f32x2*)&ob[(k + 32) * 2] : z;
    }
    __builtin_amdgcn_sched_barrier(0);          // pin issue order: coords < masks

    // ---- (2) mask loads: linear dwordx4, 1024 B contiguous per instruction
    i32x4 mk[7];
    const int ldw = lane * 4;                   // lane's dword offset
    #pragma unroll
    for (int i = 0; i < 7; ++i)
        mk[i] = *(const i32x4*)&rm[i * 256 + ldw];
    __builtin_amdgcn_sched_barrier(0);

    const int ksteps = (n >= 32) ? 2 : 1;       // wave-uniform

    // ---- (3) ex-fragment (SECOND mfma operand, carries sign): rows h=wid*16+m
    const float fh = (float)(wid * 16 + m);
    half8 a0, a1;
    #pragma unroll
    for (int j = 0; j < 8; ++j) {
        int k = quad * 8 + j;
        float val = 0.f;
        if (k <= n) {
            float cx = (k < n) ? oc0[j][1] : xl;
            float s  = (k < n) ? -0.5f  : 0.5f;
            float d  = fh - cx;
            val = s * __expf(-d * d * INV);
        }
        a0[j] = (_Float16)val;
    }
    if (ksteps == 2) {
        #pragma unroll
        for (int j = 0; j < 8; ++j) {
            int k = quad * 8 + j + 32;
            float val = 0.f;
            if (k <= n) {
                float cx = (k < n) ? oc1[j][1] : xl;
                float s  = (k < n) ? -0.5f  : 0.5f;
                float d  = fh - cx;
                val = s * __expf(-d * d * INV);
            }
            a1[j] = (_Float16)val;
        }
    }

    // ---- (4) per tile: ey-fragment (FIRST operand), swapped MFMA, ds_write_b128
    #pragma unroll
    for (int tw = 0; tw < 7; ++tw) {
        const float fw = (float)(tw * 16 + m);  // this lane's w for ey
        half8 e0;
        #pragma unroll
        for (int j = 0; j < 8; ++j) {
            int k = quad * 8 + j;
            float val = 0.f;
            if (k <= n) {
                float cy = (k < n) ? oc0[j][0] : yl;
                float d  = fw - cy;
                val = __expf(-d * d * INV);
            }
            e0[j] = (_Float16)val;
        }
        f32x4 acc = {0.f, 0.f, 0.f, 0.f};
        acc = __builtin_amdgcn_mfma_f32_16x16x32_f16(e0, a0, acc, 0, 0, 0);
        if (ksteps == 2) {
            half8 e1;
            #pragma unroll
            for (int j = 0; j < 8; ++j) {
                int k = quad * 8 + j + 32;
                float val = 0.f;
                if (k <= n) {
                    float cy = (k < n) ? oc1[j][0] : yl;
                    float d  = fw - cy;
                    val = __expf(-d * d * INV);
                }
                e1[j] = (_Float16)val;
            }
            acc = __builtin_amdgcn_mfma_f32_16x16x32_f16(e1, a1, acc, 0, 0, 0);
        }
        // lane holds out[h=m][w = tw*16 + quad*4 + 0..3] -> one b128 LDS write
        *(f32x4*)&lds[wid][m * GRID_N + tw * 16 + quad * 4] = acc;
    }

    // ---- (5) linear read-back (own wave's writes: compiler inserts lgkmcnt,
    //      no barrier needed), mask select, dwordx4 stores (full lines)
    #pragma unroll
    for (int i = 0; i < 7; ++i) {
        f32x4 v = *(const f32x4*)&lds[wid][i * 256 + ldw];
        i32x4 mm = mk[i];
        f32x4 o;
        #pragma unroll
        for (int j = 0; j < 4; ++j)
            o[j] = (mm[j] == 0) ? 0.f : (0.5f + v[j]);
        *(f32x4*)&op[i * 256 + ldw] = o;
    }
}

extern "C" void kernel_launch(void* const* d_in, const int* in_sizes, int n_in,
                              void* d_out, int out_size, void* d_ws, size_t ws_size,
                              hipStream_t stream) {
    const float* xL        = (const float*)d_in[0];
    const float* yL        = (const float*)d_in[1];
    const float* obj_list  = (const float*)d_in[2];
    const int*   obj_num   = (const int*)d_in[3];
    const int*   road_mask = (const int*)d_in[4];
    float*       out       = (float*)d_out;
    const int B = in_sizes[0];  // 2048

    goalmap_kernel<<<B, NT, 0, stream>>>(xL, yL, obj_list, obj_num, road_mask, out);
}